// Round 5
// baseline (254.449 us; speedup 1.0000x reference)
//
#include <hip/hip_runtime.h>
#include <stdint.h>

typedef short short8 __attribute__((ext_vector_type(8)));
typedef short short4_t __attribute__((ext_vector_type(4)));
typedef float f32x4 __attribute__((ext_vector_type(4)));

__device__ __forceinline__ float bf2f(unsigned short u) {
    union { unsigned int i; float f; } v; v.i = ((unsigned int)u) << 16; return v.f;
}
// round-half-up bf16 (max 0.5 ulp, 2 VALU ops)
__device__ __forceinline__ unsigned short f2bf(float f) {
    union { float f; unsigned int i; } v; v.f = f;
    return (unsigned short)((v.i + 0x8000u) >> 16);
}

// ---------------- kernel A: fused x->bf16 hi/lo + weight transpose ---------
__global__ __launch_bounds__(256) void k_pre(const float* __restrict__ x,
                                             const float* __restrict__ Wf,
                                             const float* __restrict__ Wg,
                                             const float* __restrict__ Wh,
                                             unsigned short* __restrict__ xh,
                                             unsigned short* __restrict__ xl,
                                             unsigned short* __restrict__ wTh,
                                             unsigned short* __restrict__ wTl) {
    if (blockIdx.x < 2048) {
        int gid = blockIdx.x * 256 + threadIdx.x;   // 8 elems each
        const float* src = x + (size_t)gid * 8;
        f32x4 a0 = *(const f32x4*)src;
        f32x4 a1 = *(const f32x4*)(src + 4);
        short8 sh, sl;
#pragma unroll
        for (int j = 0; j < 4; ++j) {
            unsigned short h0 = f2bf(a0[j]);
            sh[j] = (short)h0; sl[j] = (short)f2bf(a0[j] - bf2f(h0));
            unsigned short h1 = f2bf(a1[j]);
            sh[4 + j] = (short)h1; sl[4 + j] = (short)f2bf(a1[j] - bf2f(h1));
        }
        *(short8*)&xh[(size_t)gid * 8] = sh;
        *(short8*)&xl[(size_t)gid * 8] = sl;
    } else {
        int col = blockIdx.x - 2048;   // 0..319
        int k = threadIdx.x;           // 0..255
        float v;
        if (col < 32) v = Wf[k * 32 + col];
        else if (col < 64) v = Wg[k * 32 + (col - 32)];
        else v = Wh[k * 256 + (col - 64)];
        unsigned short h = f2bf(v);
        wTh[col * 256 + k] = h;
        if (col < 64) wTl[col * 256 + k] = f2bf(v - bf2f(h));
    }
}

// ---------------- kernel B: fused projections (grid 256 x 5) ---------------
// Outputs in FRAGMENT-LINEAR layouts:
//   fK/gQ: [b][t=key>>4][chunk=(ch>>3)*16+(key&15)][8]  (tile = 512 shorts)
//   hT:    [b][ch>>4][key>>5][chunk=((key&31)>>3)*16+(ch&15)][8 keys]
__global__ __launch_bounds__(256) void k_proj(
    const unsigned short* __restrict__ xh,
    const unsigned short* __restrict__ xl,
    const unsigned short* __restrict__ wTh,
    const unsigned short* __restrict__ wTl,
    const float* __restrict__ bfb,
    const float* __restrict__ bgb,
    const float* __restrict__ bhb,
    unsigned short* __restrict__ fKh,
    unsigned short* __restrict__ fKl,
    unsigned short* __restrict__ gQh,
    unsigned short* __restrict__ gQl,
    unsigned short* __restrict__ hT) {
    __shared__ short sm[4 * 64 * 72];   // 36.9 KB, both paths
    int tid = threadIdx.x;
    int wave = tid >> 6, lane = tid & 63, lq = lane & 15, quad = lane >> 4;
    int rt = blockIdx.x;
    const unsigned short* xhb = xh + (size_t)rt * 64 * 256;
    const unsigned short* xlb = xl + (size_t)rt * 64 * 256;
    f32x4 zero4 = {0.f, 0.f, 0.f, 0.f};

    if (blockIdx.y < 4) {
        // h path: [64][136] X + W tiles
        const int XO = 0, WO = 64 * 136;
        int cb = blockIdx.y;
        const unsigned short* wbase = wTh + (size_t)(64 + cb * 64) * 256;
        f32x4 acc[4] = {zero4, zero4, zero4, zero4};

        for (int ph = 0; ph < 2; ++ph) {
            int k0 = ph * 128;
            __syncthreads();
#pragma unroll
            for (int u = 0; u < 4; ++u) {
                int q = u * 256 + tid;
                int row = q >> 4, kc = q & 15;
                *(short8*)&sm[XO + row * 136 + kc * 8] =
                    *(const short8*)&xhb[row * 256 + k0 + kc * 8];
                *(short8*)&sm[WO + row * 136 + kc * 8] =
                    *(const short8*)&wbase[row * 256 + k0 + kc * 8];
            }
            __syncthreads();
#pragma unroll
            for (int ks = 0; ks < 4; ++ks) {
                short8 a = *(const short8*)&sm[XO + (wave * 16 + lq) * 136 + ks * 32 + quad * 8];
#pragma unroll
                for (int ct = 0; ct < 4; ++ct) {
                    short8 bfr = *(const short8*)&sm[WO + (lq + 16 * ct) * 136 + ks * 32 + quad * 8];
                    acc[ct] = __builtin_amdgcn_mfma_f32_16x16x32_bf16(a, bfr, acc[ct], 0, 0, 0);
                }
            }
        }

        int rowl = wave * 16 + quad * 4;
        int grow0 = rt * 64;
        int bidx = grow0 >> 12, n0 = (grow0 & 4095) + rowl;
#pragma unroll
        for (int ct = 0; ct < 4; ++ct) {
            int c = cb * 64 + lq + 16 * ct;
            float bias = bhb[c];
            short4_t pk;
#pragma unroll
            for (int r = 0; r < 4; ++r) pk[r] = (short)f2bf(acc[ct][r] + bias);
            size_t a8 = (((size_t)(bidx * 16 + (c >> 4)) * 128 + (n0 >> 5)) * 64 +
                         ((n0 & 31) >> 3) * 16 + (c & 15)) * 8 + (n0 & 7);
            *(short4_t*)&hT[a8] = pk;
        }
    } else {
        // f,g path (3-term hi/lo), [64][72] tiles
        const int XH = 0, XL = 64 * 72, WH = 2 * 64 * 72, WL = 3 * 64 * 72;
        f32x4 acc[4] = {zero4, zero4, zero4, zero4};

        for (int ph = 0; ph < 4; ++ph) {
            int k0 = ph * 64;
            __syncthreads();
#pragma unroll
            for (int u = 0; u < 2; ++u) {
                int q = u * 256 + tid;
                int row = q >> 3, kc = q & 7;
                *(short8*)&sm[XH + row * 72 + kc * 8] =
                    *(const short8*)&xhb[row * 256 + k0 + kc * 8];
                *(short8*)&sm[XL + row * 72 + kc * 8] =
                    *(const short8*)&xlb[row * 256 + k0 + kc * 8];
                *(short8*)&sm[WH + row * 72 + kc * 8] =
                    *(const short8*)&wTh[row * 256 + k0 + kc * 8];
                *(short8*)&sm[WL + row * 72 + kc * 8] =
                    *(const short8*)&wTl[row * 256 + k0 + kc * 8];
            }
            __syncthreads();
#pragma unroll
            for (int ks = 0; ks < 2; ++ks) {
                short8 ah = *(const short8*)&sm[XH + (wave * 16 + lq) * 72 + ks * 32 + quad * 8];
                short8 al = *(const short8*)&sm[XL + (wave * 16 + lq) * 72 + ks * 32 + quad * 8];
#pragma unroll
                for (int ct = 0; ct < 4; ++ct) {
                    short8 bh = *(const short8*)&sm[WH + (lq + 16 * ct) * 72 + ks * 32 + quad * 8];
                    short8 bl = *(const short8*)&sm[WL + (lq + 16 * ct) * 72 + ks * 32 + quad * 8];
                    acc[ct] = __builtin_amdgcn_mfma_f32_16x16x32_bf16(ah, bh, acc[ct], 0, 0, 0);
                    acc[ct] = __builtin_amdgcn_mfma_f32_16x16x32_bf16(al, bh, acc[ct], 0, 0, 0);
                    acc[ct] = __builtin_amdgcn_mfma_f32_16x16x32_bf16(ah, bl, acc[ct], 0, 0, 0);
                }
            }
        }

        int rowl = wave * 16 + quad * 4;
#pragma unroll
        for (int ct = 0; ct < 4; ++ct) {
            int coll = lq + 16 * ct;
#pragma unroll
            for (int r = 0; r < 4; ++r) {
                int grow = rt * 64 + rowl + r;
                int bidx = grow >> 12, n = grow & 4095;
                float v = acc[ct][r];
                size_t o = (size_t)(bidx * 256 + (n >> 4)) * 512 +
                           (((coll & 31) >> 3) * 16 + (n & 15)) * 8 + (coll & 7);
                if (coll < 32) {
                    v += bfb[coll];
                    unsigned short h = f2bf(v);
                    fKh[o] = h;
                    fKl[o] = f2bf(v - bf2f(h));
                } else {
                    int cg = coll - 32;
                    size_t og = (size_t)(bidx * 256 + (n >> 4)) * 512 +
                                ((cg >> 3) * 16 + (n & 15)) * 8 + (cg & 7);
                    v += bgb[cg];
                    unsigned short h = f2bf(v);
                    gQh[og] = h;
                    gQl[og] = f2bf(v - bf2f(h));
                }
            }
        }
    }
}

// ---------------- kernel C: flash attention (R0 + KVBLK=128 + fused split-K)
// Grid 512 x 256 thr -> (b = bid&3 [XCD affinity], qt [64-row q tile],
// ks = key half). 2 INDEPENDENT blocks/CU (the R4-proven requirement).
// 16 phases of 128 keys, ONE barrier per phase, 88 MFMA/wave/barrier
// (24 S hi/lo + 64 PV). Epilogue: both halves write partials (ks=0 -> out,
// same addresses as final; ks=1 -> pacc1), threadfence + ticket atomicAdd;
// second finisher combines partner partials (same-XCD L2), normalizes,
// applies gamma + residual. No k_combine kernel.
#define PSTR 136
__global__ __launch_bounds__(256, 2) void k_attn(
    const unsigned short* __restrict__ fKh,
    const unsigned short* __restrict__ fKl,
    const unsigned short* __restrict__ gQh,
    const unsigned short* __restrict__ gQl,
    const unsigned short* __restrict__ hT,
    const float* __restrict__ x,
    const float* __restrict__ gam_p,
    float* __restrict__ out,
    float* __restrict__ pacc1,
    float* __restrict__ pl,
    int* __restrict__ flags) {
    __shared__ short Ps[2][64 * PSTR];   // 34.8 KB dbuf P (64x128 pad 136)
    __shared__ short Fb[2][2][4096];     // 32 KB dbuf f hi/lo (128x32 frag-linear)
    __shared__ float Lql[64];            // per-row l of this half
    __shared__ int tick_s;
    int tid = threadIdx.x;
    int wave = tid >> 6, lane = tid & 63, lq = lane & 15, quad = lane >> 4;
    int b = blockIdx.x & 3;
    int rest = blockIdx.x >> 2;
    int qt = rest & 63;
    int ks = rest >> 6;                  // 0 or 1
    int lchunk = quad * 16 + lq;         // fragment chunk index for this lane

    const unsigned short* fhB = fKh + (size_t)b * 131072;
    const unsigned short* flB = fKl + (size_t)b * 131072;
    const unsigned short* hB  = hT + (size_t)b * 1048576;

    f32x4 zero4 = {0.f, 0.f, 0.f, 0.f};
    f32x4 acc[16];                       // [rb(4)][ct(4)]
#pragma unroll
    for (int i = 0; i < 16; ++i) acc[i] = zero4;
    float l_part[4] = {0.f, 0.f, 0.f, 0.f};

    // g A-frags (fragment-linear tile)
    int gtile = b * 256 + qt * 4 + wave;
    short8 ghfrag = *(const short8*)&gQh[(size_t)gtile * 512 + lchunk * 8];
    short8 glfrag = *(const short8*)&gQl[(size_t)gtile * 512 + lchunk * 8];

    int ft_base = ks * 65536;            // f shorts offset of this key half

    // ---- prologue: stage f(0): 8 tiles = 4096 shorts per hi/lo ----
    *(short8*)&Fb[0][0][tid * 8]        = *(const short8*)&fhB[ft_base + tid * 8];
    *(short8*)&Fb[0][0][2048 + tid * 8] = *(const short8*)&fhB[ft_base + 2048 + tid * 8];
    *(short8*)&Fb[0][1][tid * 8]        = *(const short8*)&flB[ft_base + tid * 8];
    *(short8*)&Fb[0][1][2048 + tid * 8] = *(const short8*)&flB[ft_base + 2048 + tid * 8];
    __syncthreads();

    for (int t = 0; t < 16; ++t) {
        int p = t & 1;
        // ---- next-f prefetch (regs) ----
        size_t gn = (size_t)ft_base + (size_t)(t < 15 ? t + 1 : t) * 4096;
        short8 fn0 = *(const short8*)&fhB[gn + tid * 8];
        short8 fn1 = *(const short8*)&fhB[gn + 2048 + tid * 8];
        short8 fn2 = *(const short8*)&flB[gn + tid * 8];
        short8 fn3 = *(const short8*)&flB[gn + 2048 + tid * 8];

        // ---- hT B-frags: 4 ct x 4 kk, coalesced 1KB tiles ----
        int k0 = ks * 64 + t * 4;        // key-group (32 keys) base
        short8 hb[4][4];
#pragma unroll
        for (int ct = 0; ct < 4; ++ct) {
            int ctile = wave * 4 + ct;
#pragma unroll
            for (int kk = 0; kk < 4; ++kk)
                hb[ct][kk] = *(const short8*)
                    &hB[(((size_t)ctile * 128 + k0 + kk) * 64 + lchunk) * 8];
        }

        // ---- S = g.f^T (3-term hi/lo), 8 independent tiles ----
        f32x4 S[8];
        __builtin_amdgcn_s_setprio(1);
#pragma unroll
        for (int u = 0; u < 8; ++u) {
            short8 fh = *(const short8*)&Fb[p][0][u * 512 + lchunk * 8];
            short8 fl = *(const short8*)&Fb[p][1][u * 512 + lchunk * 8];
            S[u] = __builtin_amdgcn_mfma_f32_16x16x32_bf16(ghfrag, fh, zero4, 0, 0, 0);
            S[u] = __builtin_amdgcn_mfma_f32_16x16x32_bf16(glfrag, fh, S[u], 0, 0, 0);
            S[u] = __builtin_amdgcn_mfma_f32_16x16x32_bf16(ghfrag, fl, S[u], 0, 0, 0);
        }
        __builtin_amdgcn_s_setprio(0);

        // ---- P = exp(S), per-lane l ----
#pragma unroll
        for (int u = 0; u < 8; ++u)
#pragma unroll
            for (int r = 0; r < 4; ++r) {
                float e = __expf(S[u][r]);
                S[u][r] = e;
                l_part[r] += e;
            }

        // ---- P (bf16) to LDS ----
#pragma unroll
        for (int u = 0; u < 8; ++u)
#pragma unroll
            for (int r = 0; r < 4; ++r)
                Ps[p][(wave * 16 + quad * 4 + r) * PSTR + u * 16 + lq] =
                    (short)f2bf(S[u][r]);

        // ---- stage next f ----
        *(short8*)&Fb[1 - p][0][tid * 8] = fn0;
        *(short8*)&Fb[1 - p][0][2048 + tid * 8] = fn1;
        *(short8*)&Fb[1 - p][1][tid * 8] = fn2;
        *(short8*)&Fb[1 - p][1][2048 + tid * 8] = fn3;

        __syncthreads();   // P[p] + Fb[1-p] visible; single barrier per phase

        // ---- PV: all 64 rows x this wave's 64 channels x 128 keys ----
        __builtin_amdgcn_s_setprio(1);
#pragma unroll
        for (int rb = 0; rb < 4; ++rb) {
            short8 pa[4];
#pragma unroll
            for (int kk = 0; kk < 4; ++kk)
                pa[kk] = *(const short8*)&Ps[p][(rb * 16 + lq) * PSTR + kk * 32 + quad * 8];
#pragma unroll
            for (int kk = 0; kk < 4; ++kk)
#pragma unroll
                for (int ct = 0; ct < 4; ++ct)
                    acc[rb * 4 + ct] = __builtin_amdgcn_mfma_f32_16x16x32_bf16(
                        pa[kk], hb[ct][kk], acc[rb * 4 + ct], 0, 0, 0);
        }
        __builtin_amdgcn_s_setprio(0);
    }

    // ---- epilogue: per-row l of this half (reduce over lq lanes) ----
#pragma unroll
    for (int r = 0; r < 4; ++r) {
        float s = l_part[r];
        s += __shfl_xor(s, 1);
        s += __shfl_xor(s, 2);
        s += __shfl_xor(s, 4);
        s += __shfl_xor(s, 8);
        if (lq == 0) Lql[wave * 16 + quad * 4 + r] = s;
    }
    __syncthreads();

    // ---- write partials (ks=0 -> out [same addresses as final], ks=1 -> pacc1)
    int pair = b * 64 + qt;
    size_t pbase = (size_t)pair * 64 * 256;
    float* mypart = ks ? pacc1 : out;
#pragma unroll
    for (int rb = 0; rb < 4; ++rb)
#pragma unroll
        for (int ct = 0; ct < 4; ++ct) {
            int c = wave * 64 + ct * 16 + lq;
#pragma unroll
            for (int r = 0; r < 4; ++r) {
                int n = rb * 16 + quad * 4 + r;
                mypart[pbase + (size_t)n * 256 + c] = acc[rb * 4 + ct][r];
            }
        }
    if (tid < 64) pl[(size_t)(ks * 256 + pair) * 64 + tid] = Lql[tid];

    __threadfence();
    __syncthreads();
    if (tid == 0) tick_s = atomicAdd(&flags[pair], 1);
    __syncthreads();
    if (tick_s == 0) return;     // partner will combine
    __threadfence();             // acquire partner's partials

    // ---- combine: partner partials + own acc -> normalize, gamma, residual
    const float* opart = ks ? out : pacc1;
    const float* plp = &pl[(size_t)((1 - ks) * 256 + pair) * 64];
    float gam = gam_p[0];
#pragma unroll
    for (int rb = 0; rb < 4; ++rb)
#pragma unroll
        for (int r = 0; r < 4; ++r) {
            int n = rb * 16 + quad * 4 + r;
            float linv = 1.0f / (Lql[n] + plp[n]);
            size_t rowo = pbase + (size_t)n * 256;   // == final out row base
#pragma unroll
            for (int ct = 0; ct < 4; ++ct) {
                int c = wave * 64 + ct * 16 + lq;
                float o = acc[rb * 4 + ct][r] + opart[rowo + c];
                out[rowo + c] = gam * o * linv + x[rowo + c];
            }
        }
}

extern "C" void kernel_launch(void* const* d_in, const int* in_sizes, int n_in,
                              void* d_out, int out_size, void* d_ws, size_t ws_size,
                              hipStream_t stream) {
    const float* x   = (const float*)d_in[0];
    const float* Wf  = (const float*)d_in[1];
    const float* bfb = (const float*)d_in[2];
    const float* Wg  = (const float*)d_in[3];
    const float* bgb = (const float*)d_in[4];
    const float* Wh  = (const float*)d_in[5];
    const float* bhb = (const float*)d_in[6];
    const float* gam = (const float*)d_in[7];
    float* out = (float*)d_out;

    char* ws = (char*)d_ws;
    const size_t MI = 1u << 20;
    unsigned short* xh  = (unsigned short*)(ws);                  // 8 MiB
    unsigned short* xl  = (unsigned short*)(ws + 8 * MI);         // 8 MiB
    unsigned short* fKh = (unsigned short*)(ws + 16 * MI);        // 1 MiB
    unsigned short* fKl = (unsigned short*)(ws + 17 * MI);        // 1 MiB
    unsigned short* gQh = (unsigned short*)(ws + 18 * MI);        // 1 MiB
    unsigned short* gQl = (unsigned short*)(ws + 19 * MI);        // 1 MiB
    unsigned short* hT  = (unsigned short*)(ws + 20 * MI);        // 8 MiB
    unsigned short* wTh = (unsigned short*)(ws + 28 * MI);        // 160 KiB
    unsigned short* wTl = (unsigned short*)(ws + 28 * MI + 160 * 1024); // 32 KiB
    float* pacc1 = (float*)(ws + 29 * MI);                        // 16 MiB
    float* pl    = (float*)(ws + 45 * MI);                        // 128 KiB
    int*   flags = (int*)(ws + 45 * MI + 128 * 1024);             // 1 KiB

    hipMemsetAsync(flags, 0, 256 * sizeof(int), stream);
    k_pre<<<dim3(2368), dim3(256), 0, stream>>>(x, Wf, Wg, Wh, xh, xl, wTh, wTl);
    k_proj<<<dim3(256, 5), dim3(256), 0, stream>>>(xh, xl, wTh, wTl, bfb, bgb, bhb,
                                                   fKh, fKl, gQh, gQl, hT);
    k_attn<<<dim3(512), dim3(256), 0, stream>>>(fKh, fKl, gQh, gQl, hT,
                                                x, gam, out, pacc1, pl, flags);
}

// Round 6
// 159.742 us; speedup vs baseline: 1.5929x; 1.5929x over previous
//
#include <hip/hip_runtime.h>
#include <stdint.h>

typedef short short8 __attribute__((ext_vector_type(8)));
typedef short short4_t __attribute__((ext_vector_type(4)));
typedef float f32x4 __attribute__((ext_vector_type(4)));

__device__ __forceinline__ float bf2f(unsigned short u) {
    union { unsigned int i; float f; } v; v.i = ((unsigned int)u) << 16; return v.f;
}
// round-half-up bf16 (max 0.5 ulp, 2 VALU ops)
__device__ __forceinline__ unsigned short f2bf(float f) {
    union { float f; unsigned int i; } v; v.f = f;
    return (unsigned short)((v.i + 0x8000u) >> 16);
}

// ---------------- kernel A: fused x->bf16 hi/lo + weight transpose ---------
__global__ __launch_bounds__(256) void k_pre(const float* __restrict__ x,
                                             const float* __restrict__ Wf,
                                             const float* __restrict__ Wg,
                                             const float* __restrict__ Wh,
                                             unsigned short* __restrict__ xh,
                                             unsigned short* __restrict__ xl,
                                             unsigned short* __restrict__ wTh,
                                             unsigned short* __restrict__ wTl) {
    if (blockIdx.x < 2048) {
        int gid = blockIdx.x * 256 + threadIdx.x;   // 8 elems each
        const float* src = x + (size_t)gid * 8;
        f32x4 a0 = *(const f32x4*)src;
        f32x4 a1 = *(const f32x4*)(src + 4);
        short8 sh, sl;
#pragma unroll
        for (int j = 0; j < 4; ++j) {
            unsigned short h0 = f2bf(a0[j]);
            sh[j] = (short)h0; sl[j] = (short)f2bf(a0[j] - bf2f(h0));
            unsigned short h1 = f2bf(a1[j]);
            sh[4 + j] = (short)h1; sl[4 + j] = (short)f2bf(a1[j] - bf2f(h1));
        }
        *(short8*)&xh[(size_t)gid * 8] = sh;
        *(short8*)&xl[(size_t)gid * 8] = sl;
    } else {
        int col = blockIdx.x - 2048;   // 0..319
        int k = threadIdx.x;           // 0..255
        float v;
        if (col < 32) v = Wf[k * 32 + col];
        else if (col < 64) v = Wg[k * 32 + (col - 32)];
        else v = Wh[k * 256 + (col - 64)];
        unsigned short h = f2bf(v);
        wTh[col * 256 + k] = h;
        if (col < 64) wTl[col * 256 + k] = f2bf(v - bf2f(h));
    }
}

// ---------------- kernel B: fused projections (grid 256 x 5) ---------------
// Outputs in FRAGMENT-LINEAR layouts:
//   fK/gQ: [b][t=key>>4][chunk=(ch>>3)*16+(key&15)][8]  (tile = 512 shorts)
//   hT:    [b][ch>>4][key>>5][chunk=((key&31)>>3)*16+(ch&15)][8 keys]
__global__ __launch_bounds__(256) void k_proj(
    const unsigned short* __restrict__ xh,
    const unsigned short* __restrict__ xl,
    const unsigned short* __restrict__ wTh,
    const unsigned short* __restrict__ wTl,
    const float* __restrict__ bfb,
    const float* __restrict__ bgb,
    const float* __restrict__ bhb,
    unsigned short* __restrict__ fKh,
    unsigned short* __restrict__ fKl,
    unsigned short* __restrict__ gQh,
    unsigned short* __restrict__ gQl,
    unsigned short* __restrict__ hT) {
    __shared__ short sm[4 * 64 * 72];   // 36.9 KB, both paths
    int tid = threadIdx.x;
    int wave = tid >> 6, lane = tid & 63, lq = lane & 15, quad = lane >> 4;
    int rt = blockIdx.x;
    const unsigned short* xhb = xh + (size_t)rt * 64 * 256;
    const unsigned short* xlb = xl + (size_t)rt * 64 * 256;
    f32x4 zero4 = {0.f, 0.f, 0.f, 0.f};

    if (blockIdx.y < 4) {
        // h path: [64][136] X + W tiles
        const int XO = 0, WO = 64 * 136;
        int cb = blockIdx.y;
        const unsigned short* wbase = wTh + (size_t)(64 + cb * 64) * 256;
        f32x4 acc[4] = {zero4, zero4, zero4, zero4};

        for (int ph = 0; ph < 2; ++ph) {
            int k0 = ph * 128;
            __syncthreads();
#pragma unroll
            for (int u = 0; u < 4; ++u) {
                int q = u * 256 + tid;
                int row = q >> 4, kc = q & 15;
                *(short8*)&sm[XO + row * 136 + kc * 8] =
                    *(const short8*)&xhb[row * 256 + k0 + kc * 8];
                *(short8*)&sm[WO + row * 136 + kc * 8] =
                    *(const short8*)&wbase[row * 256 + k0 + kc * 8];
            }
            __syncthreads();
#pragma unroll
            for (int ks = 0; ks < 4; ++ks) {
                short8 a = *(const short8*)&sm[XO + (wave * 16 + lq) * 136 + ks * 32 + quad * 8];
#pragma unroll
                for (int ct = 0; ct < 4; ++ct) {
                    short8 bfr = *(const short8*)&sm[WO + (lq + 16 * ct) * 136 + ks * 32 + quad * 8];
                    acc[ct] = __builtin_amdgcn_mfma_f32_16x16x32_bf16(a, bfr, acc[ct], 0, 0, 0);
                }
            }
        }

        int rowl = wave * 16 + quad * 4;
        int grow0 = rt * 64;
        int bidx = grow0 >> 12, n0 = (grow0 & 4095) + rowl;
#pragma unroll
        for (int ct = 0; ct < 4; ++ct) {
            int c = cb * 64 + lq + 16 * ct;
            float bias = bhb[c];
            short4_t pk;
#pragma unroll
            for (int r = 0; r < 4; ++r) pk[r] = (short)f2bf(acc[ct][r] + bias);
            size_t a8 = (((size_t)(bidx * 16 + (c >> 4)) * 128 + (n0 >> 5)) * 64 +
                         ((n0 & 31) >> 3) * 16 + (c & 15)) * 8 + (n0 & 7);
            *(short4_t*)&hT[a8] = pk;
        }
    } else {
        // f,g path (3-term hi/lo), [64][72] tiles
        const int XH = 0, XL = 64 * 72, WH = 2 * 64 * 72, WL = 3 * 64 * 72;
        f32x4 acc[4] = {zero4, zero4, zero4, zero4};

        for (int ph = 0; ph < 4; ++ph) {
            int k0 = ph * 64;
            __syncthreads();
#pragma unroll
            for (int u = 0; u < 2; ++u) {
                int q = u * 256 + tid;
                int row = q >> 3, kc = q & 7;
                *(short8*)&sm[XH + row * 72 + kc * 8] =
                    *(const short8*)&xhb[row * 256 + k0 + kc * 8];
                *(short8*)&sm[XL + row * 72 + kc * 8] =
                    *(const short8*)&xlb[row * 256 + k0 + kc * 8];
                *(short8*)&sm[WH + row * 72 + kc * 8] =
                    *(const short8*)&wTh[row * 256 + k0 + kc * 8];
                *(short8*)&sm[WL + row * 72 + kc * 8] =
                    *(const short8*)&wTl[row * 256 + k0 + kc * 8];
            }
            __syncthreads();
#pragma unroll
            for (int ks = 0; ks < 2; ++ks) {
                short8 ah = *(const short8*)&sm[XH + (wave * 16 + lq) * 72 + ks * 32 + quad * 8];
                short8 al = *(const short8*)&sm[XL + (wave * 16 + lq) * 72 + ks * 32 + quad * 8];
#pragma unroll
                for (int ct = 0; ct < 4; ++ct) {
                    short8 bh = *(const short8*)&sm[WH + (lq + 16 * ct) * 72 + ks * 32 + quad * 8];
                    short8 bl = *(const short8*)&sm[WL + (lq + 16 * ct) * 72 + ks * 32 + quad * 8];
                    acc[ct] = __builtin_amdgcn_mfma_f32_16x16x32_bf16(ah, bh, acc[ct], 0, 0, 0);
                    acc[ct] = __builtin_amdgcn_mfma_f32_16x16x32_bf16(al, bh, acc[ct], 0, 0, 0);
                    acc[ct] = __builtin_amdgcn_mfma_f32_16x16x32_bf16(ah, bl, acc[ct], 0, 0, 0);
                }
            }
        }

        int rowl = wave * 16 + quad * 4;
#pragma unroll
        for (int ct = 0; ct < 4; ++ct) {
            int coll = lq + 16 * ct;
#pragma unroll
            for (int r = 0; r < 4; ++r) {
                int grow = rt * 64 + rowl + r;
                int bidx = grow >> 12, n = grow & 4095;
                float v = acc[ct][r];
                size_t o = (size_t)(bidx * 256 + (n >> 4)) * 512 +
                           (((coll & 31) >> 3) * 16 + (n & 15)) * 8 + (coll & 7);
                if (coll < 32) {
                    v += bfb[coll];
                    unsigned short h = f2bf(v);
                    fKh[o] = h;
                    fKl[o] = f2bf(v - bf2f(h));
                } else {
                    int cg = coll - 32;
                    size_t og = (size_t)(bidx * 256 + (n >> 4)) * 512 +
                                ((cg >> 3) * 16 + (n & 15)) * 8 + (cg & 7);
                    v += bgb[cg];
                    unsigned short h = f2bf(v);
                    gQh[og] = h;
                    gQl[og] = f2bf(v - bf2f(h));
                }
            }
        }
    }
}

// ---------------- kernel C: flash attention (R0 shape, 3-way key split) ----
// EXACT R0 per-block structure (256 thr, 4 waves, 64 q-rows, 64-key phases,
// one barrier per phase, 44 MFMA/wave/phase, VGPR ~92, LDS 34.8 KB).
// Only change: grid 768 -> 3 INDEPENDENT blocks per CU (the R4-proven
// cross-block-overlap mechanism, now 1.5x deeper). Key range split 3 ways
// (uneven 22/21/21 phases); partials: ksn=0 -> out, 1 -> pacc1, 2 -> pacc2.
#define PSTR 72
__global__ __launch_bounds__(256, 2) void k_attn(
    const unsigned short* __restrict__ fKh,
    const unsigned short* __restrict__ fKl,
    const unsigned short* __restrict__ gQh,
    const unsigned short* __restrict__ gQl,
    const unsigned short* __restrict__ hT,
    float* __restrict__ pacc0,
    float* __restrict__ pacc1,
    float* __restrict__ pacc2,
    float* __restrict__ pl) {
    __shared__ short Ps[2][64 * PSTR];   // 18.4 KB dbuf P (64x64 pad 72)
    __shared__ short Fb[2][2][2048];     // 16 KB dbuf f hi/lo (64x32 frag-linear)
    int tid = threadIdx.x;
    int wave = tid >> 6, lane = tid & 63, lq = lane & 15, quad = lane >> 4;
    int b = blockIdx.x & 3;              // constant per XCD (bid%8 -> XCD)
    int rest = blockIdx.x >> 2;
    int qt = rest & 63;
    int ksn = rest >> 6;                 // 0,1,2 (key third)

    int kt0 = (ksn == 0) ? 0 : (ksn == 1 ? 22 : 43);
    int nkt = (ksn == 0) ? 22 : 21;      // 22+21+21 = 64 phases of 64 keys

    const unsigned short* fhB = fKh + (size_t)b * 131072;
    const unsigned short* flB = fKl + (size_t)b * 131072;
    const unsigned short* hB  = hT + (size_t)b * 1048576;
    float* pacc = (ksn == 0) ? pacc0 : (ksn == 1 ? pacc1 : pacc2);
    float* plb  = pl + ksn * 16384;

    int qrow0 = qt * 64 + wave * 16;
    int lchunk = quad * 16 + lq;         // fragment chunk index for this lane

    f32x4 zero4 = {0.f, 0.f, 0.f, 0.f};
    f32x4 acc[16];                       // [rb(4)][ct(4)]
#pragma unroll
    for (int i = 0; i < 16; ++i) acc[i] = zero4;
    float l_part[4] = {0.f, 0.f, 0.f, 0.f};

    // g A-frags (fragment-linear tile; gQh/gQl are raw pointers -> include b)
    int gtile = b * 256 + qt * 4 + wave;
    short8 ghfrag = *(const short8*)&gQh[(size_t)gtile * 512 + lchunk * 8];
    short8 glfrag = *(const short8*)&gQl[(size_t)gtile * 512 + lchunk * 8];

    // fhB/flB are ALREADY batch-offset: tile index must NOT include b.
    int ft0 = kt0 * 4;                   // first 16-key f tile of this third
    // prologue: stage f(kt=0): 4 tiles = 2048 shorts, linear copy
    *(short8*)&Fb[0][0][tid * 8] = *(const short8*)&fhB[(size_t)ft0 * 512 + tid * 8];
    *(short8*)&Fb[0][1][tid * 8] = *(const short8*)&flB[(size_t)ft0 * 512 + tid * 8];
    __syncthreads();

    for (int kt = 0; kt < nkt; ++kt) {
        int p = kt & 1;
        // ---- next-f prefetch (linear) ----
        int nft = (kt0 + (kt < nkt - 1 ? kt + 1 : kt)) * 4;
        short8 fnh = *(const short8*)&fhB[(size_t)nft * 512 + tid * 8];
        short8 fnl = *(const short8*)&flB[(size_t)nft * 512 + tid * 8];

        // ---- hT B-frags: coalesced 1KB tile loads, unique per wave ----
        int k0 = (kt0 + kt) * 2;         // key-group (32 keys) base
        short8 hb[4][2];
#pragma unroll
        for (int ct = 0; ct < 4; ++ct) {
            int ctile = wave * 4 + ct;
#pragma unroll
            for (int kk = 0; kk < 2; ++kk)
                hb[ct][kk] = *(const short8*)
                    &hB[(((size_t)ctile * 128 + k0 + kk) * 64 + lchunk) * 8];
        }

        // ---- S = g.f^T (3-term hi/lo) from Fb[p] ----
        f32x4 S[4];
#pragma unroll
        for (int t = 0; t < 4; ++t) {
            short8 fh = *(const short8*)&Fb[p][0][t * 512 + lchunk * 8];
            short8 fl = *(const short8*)&Fb[p][1][t * 512 + lchunk * 8];
            S[t] = __builtin_amdgcn_mfma_f32_16x16x32_bf16(ghfrag, fh, zero4, 0, 0, 0);
            S[t] = __builtin_amdgcn_mfma_f32_16x16x32_bf16(glfrag, fh, S[t], 0, 0, 0);
            S[t] = __builtin_amdgcn_mfma_f32_16x16x32_bf16(ghfrag, fl, S[t], 0, 0, 0);
        }

        // ---- P = exp(S), per-lane l ----
#pragma unroll
        for (int t = 0; t < 4; ++t)
#pragma unroll
            for (int r = 0; r < 4; ++r) S[t][r] = __expf(S[t][r]);
#pragma unroll
        for (int r = 0; r < 4; ++r)
            l_part[r] += (S[0][r] + S[1][r]) + (S[2][r] + S[3][r]);

        // ---- P (bf16) to LDS (row-major, stride 72) ----
#pragma unroll
        for (int t = 0; t < 4; ++t)
#pragma unroll
            for (int r = 0; r < 4; ++r)
                Ps[p][(wave * 16 + quad * 4 + r) * PSTR + lq + 16 * t] =
                    (short)f2bf(S[t][r]);

        // ---- stage next f ----
        *(short8*)&Fb[1 - p][0][tid * 8] = fnh;
        *(short8*)&Fb[1 - p][1][tid * 8] = fnl;

        __syncthreads();   // P[p] + Fb[1-p] visible; single barrier per kt

        // ---- PV: all 64 rows x this wave's 64 channels ----
#pragma unroll
        for (int rb = 0; rb < 4; ++rb) {
            short8 pa0 = *(const short8*)&Ps[p][(rb * 16 + lq) * PSTR + quad * 8];
            short8 pa1 = *(const short8*)&Ps[p][(rb * 16 + lq) * PSTR + 32 + quad * 8];
#pragma unroll
            for (int ct = 0; ct < 4; ++ct) {
                acc[rb * 4 + ct] = __builtin_amdgcn_mfma_f32_16x16x32_bf16(pa0, hb[ct][0], acc[rb * 4 + ct], 0, 0, 0);
                acc[rb * 4 + ct] = __builtin_amdgcn_mfma_f32_16x16x32_bf16(pa1, hb[ct][1], acc[rb * 4 + ct], 0, 0, 0);
            }
        }
    }

    // ---- epilogue: reduce l over lq lanes, write partials ----
#pragma unroll
    for (int r = 0; r < 4; ++r) {
        float s = l_part[r];
        s += __shfl_xor(s, 1);
        s += __shfl_xor(s, 2);
        s += __shfl_xor(s, 4);
        s += __shfl_xor(s, 8);
        if (lq == 0)
            plb[b * 4096 + qrow0 + quad * 4 + r] = s;
    }
#pragma unroll
    for (int rb = 0; rb < 4; ++rb)
#pragma unroll
        for (int ct = 0; ct < 4; ++ct) {
            int c = wave * 64 + ct * 16 + lq;
#pragma unroll
            for (int r = 0; r < 4; ++r) {
                int n = qt * 64 + rb * 16 + quad * 4 + r;
                pacc[((size_t)(b * 4096 + n)) * 256 + c] = acc[rb * 4 + ct][r];
            }
        }
}

// ---------------- kernel D: combine 3 partials + residual ------------------
__global__ __launch_bounds__(256) void k_combine(
    const float* __restrict__ x,
    const float* __restrict__ gam_p,
    const float* __restrict__ pacc1,
    const float* __restrict__ pacc2,
    const float* __restrict__ pl,
    float* __restrict__ out) {
    int gid = blockIdx.x * 256 + threadIdx.x;
    int row = gid >> 6;
    f32x4 a0 = *(const f32x4*)&out[(size_t)gid * 4];
    f32x4 a1 = *(const f32x4*)&pacc1[(size_t)gid * 4];
    f32x4 a2 = *(const f32x4*)&pacc2[(size_t)gid * 4];
    f32x4 xv = *(const f32x4*)&x[(size_t)gid * 4];
    float linv = 1.0f / (pl[row] + pl[16384 + row] + pl[32768 + row]);
    float gam = gam_p[0];
    f32x4 o;
#pragma unroll
    for (int j = 0; j < 4; ++j) o[j] = gam * (((a0[j] + a1[j]) + a2[j]) * linv) + xv[j];
    *(f32x4*)&out[(size_t)gid * 4] = o;
}

extern "C" void kernel_launch(void* const* d_in, const int* in_sizes, int n_in,
                              void* d_out, int out_size, void* d_ws, size_t ws_size,
                              hipStream_t stream) {
    const float* x   = (const float*)d_in[0];
    const float* Wf  = (const float*)d_in[1];
    const float* bfb = (const float*)d_in[2];
    const float* Wg  = (const float*)d_in[3];
    const float* bgb = (const float*)d_in[4];
    const float* Wh  = (const float*)d_in[5];
    const float* bhb = (const float*)d_in[6];
    const float* gam = (const float*)d_in[7];
    float* out = (float*)d_out;

    char* ws = (char*)d_ws;
    const size_t MI = 1u << 20;
    unsigned short* xh  = (unsigned short*)(ws);                  // 8 MiB (dead after k_proj)
    unsigned short* xl  = (unsigned short*)(ws + 8 * MI);         // 8 MiB (dead after k_proj)
    unsigned short* fKh = (unsigned short*)(ws + 16 * MI);        // 1 MiB
    unsigned short* fKl = (unsigned short*)(ws + 17 * MI);        // 1 MiB
    unsigned short* gQh = (unsigned short*)(ws + 18 * MI);        // 1 MiB
    unsigned short* gQl = (unsigned short*)(ws + 19 * MI);        // 1 MiB
    unsigned short* hT  = (unsigned short*)(ws + 20 * MI);        // 8 MiB
    unsigned short* wTh = (unsigned short*)(ws + 28 * MI);        // 160 KiB
    unsigned short* wTl = (unsigned short*)(ws + 28 * MI + 160 * 1024); // 32 KiB
    float* pacc1 = (float*)(ws + 29 * MI);                        // 16 MiB
    float* pacc2 = (float*)(ws);                                  // 16 MiB overlay on xh+xl
    float* pl    = (float*)(ws + 45 * MI);                        // 192 KiB (3 x 16384 f32)

    k_pre<<<dim3(2368), dim3(256), 0, stream>>>(x, Wf, Wg, Wh, xh, xl, wTh, wTl);
    k_proj<<<dim3(256, 5), dim3(256), 0, stream>>>(xh, xl, wTh, wTl, bfb, bgb, bhb,
                                                   fKh, fKl, gQh, gQl, hT);
    k_attn<<<dim3(768), dim3(256), 0, stream>>>(fKh, fKl, gQh, gQl, hT,
                                                out, pacc1, pacc2, pl);
    k_combine<<<dim3(4096), dim3(256), 0, stream>>>(x, gam, pacc1, pacc2, pl, out);
}

// Round 7
// 154.072 us; speedup vs baseline: 1.6515x; 1.0368x over previous
//
#include <hip/hip_runtime.h>
#include <stdint.h>

typedef short short8 __attribute__((ext_vector_type(8)));
typedef short short4_t __attribute__((ext_vector_type(4)));
typedef float f32x4 __attribute__((ext_vector_type(4)));

__device__ __forceinline__ float bf2f(unsigned short u) {
    union { unsigned int i; float f; } v; v.i = ((unsigned int)u) << 16; return v.f;
}
// round-half-up bf16 (max 0.5 ulp, 2 VALU ops)
__device__ __forceinline__ unsigned short f2bf(float f) {
    union { float f; unsigned int i; } v; v.f = f;
    return (unsigned short)((v.i + 0x8000u) >> 16);
}

// ---------------- kernel A: weight transpose only (x-conversion moved into
// k_proj). Grid 320 x 256 thr.
__global__ __launch_bounds__(256) void k_prew(const float* __restrict__ Wf,
                                              const float* __restrict__ Wg,
                                              const float* __restrict__ Wh,
                                              unsigned short* __restrict__ wTh,
                                              unsigned short* __restrict__ wTl) {
    int col = blockIdx.x;              // 0..319
    int k = threadIdx.x;               // 0..255
    float v;
    if (col < 32) v = Wf[k * 32 + col];
    else if (col < 64) v = Wg[k * 32 + (col - 32)];
    else v = Wh[k * 256 + (col - 64)];
    unsigned short h = f2bf(v);
    wTh[col * 256 + k] = h;
    if (col < 64) wTl[col * 256 + k] = f2bf(v - bf2f(h));
}

// ---------------- kernel B: fused projections (grid 256 x 5) ---------------
// Reads x (f32) DIRECTLY, converting to bf16 hi/lo during LDS staging
// (k_pre's x pass eliminated). Outputs in FRAGMENT-LINEAR layouts:
//   fK/gQ: [b][t=key>>4][chunk=(ch>>3)*16+(key&15)][8]  (tile = 512 shorts)
//   hT:    [b][ch>>4][key>>5][chunk=((key&31)>>3)*16+(ch&15)][8 keys]
__global__ __launch_bounds__(256) void k_proj(
    const float* __restrict__ x,
    const unsigned short* __restrict__ wTh,
    const unsigned short* __restrict__ wTl,
    const float* __restrict__ bfb,
    const float* __restrict__ bgb,
    const float* __restrict__ bhb,
    unsigned short* __restrict__ fKh,
    unsigned short* __restrict__ fKl,
    unsigned short* __restrict__ gQh,
    unsigned short* __restrict__ gQl,
    unsigned short* __restrict__ hT) {
    __shared__ short sm[4 * 64 * 72];   // 36.9 KB, both paths
    int tid = threadIdx.x;
    int wave = tid >> 6, lane = tid & 63, lq = lane & 15, quad = lane >> 4;
    int rt = blockIdx.x;
    const float* xb = x + (size_t)rt * 64 * 256;
    f32x4 zero4 = {0.f, 0.f, 0.f, 0.f};

    if (blockIdx.y < 4) {
        // h path: [64][136] X + W tiles (hi only)
        const int XO = 0, WO = 64 * 136;
        int cb = blockIdx.y;
        const unsigned short* wbase = wTh + (size_t)(64 + cb * 64) * 256;
        f32x4 acc[4] = {zero4, zero4, zero4, zero4};

        for (int ph = 0; ph < 2; ++ph) {
            int k0 = ph * 128;
            __syncthreads();
#pragma unroll
            for (int u = 0; u < 4; ++u) {
                int q = u * 256 + tid;
                int row = q >> 4, kc = q & 15;
                const float* xs = &xb[row * 256 + k0 + kc * 8];
                f32x4 a0 = *(const f32x4*)xs;
                f32x4 a1 = *(const f32x4*)(xs + 4);
                short8 sh;
#pragma unroll
                for (int j = 0; j < 4; ++j) {
                    sh[j] = (short)f2bf(a0[j]);
                    sh[4 + j] = (short)f2bf(a1[j]);
                }
                *(short8*)&sm[XO + row * 136 + kc * 8] = sh;
                *(short8*)&sm[WO + row * 136 + kc * 8] =
                    *(const short8*)&wbase[row * 256 + k0 + kc * 8];
            }
            __syncthreads();
#pragma unroll
            for (int ks = 0; ks < 4; ++ks) {
                short8 a = *(const short8*)&sm[XO + (wave * 16 + lq) * 136 + ks * 32 + quad * 8];
#pragma unroll
                for (int ct = 0; ct < 4; ++ct) {
                    short8 bfr = *(const short8*)&sm[WO + (lq + 16 * ct) * 136 + ks * 32 + quad * 8];
                    acc[ct] = __builtin_amdgcn_mfma_f32_16x16x32_bf16(a, bfr, acc[ct], 0, 0, 0);
                }
            }
        }

        int rowl = wave * 16 + quad * 4;
        int grow0 = rt * 64;
        int bidx = grow0 >> 12, n0 = (grow0 & 4095) + rowl;
#pragma unroll
        for (int ct = 0; ct < 4; ++ct) {
            int c = cb * 64 + lq + 16 * ct;
            float bias = bhb[c];
            short4_t pk;
#pragma unroll
            for (int r = 0; r < 4; ++r) pk[r] = (short)f2bf(acc[ct][r] + bias);
            size_t a8 = (((size_t)(bidx * 16 + (c >> 4)) * 128 + (n0 >> 5)) * 64 +
                         ((n0 & 31) >> 3) * 16 + (c & 15)) * 8 + (n0 & 7);
            *(short4_t*)&hT[a8] = pk;
        }
    } else {
        // f,g path (3-term hi/lo), [64][72] tiles
        const int XH = 0, XL = 64 * 72, WH = 2 * 64 * 72, WL = 3 * 64 * 72;
        f32x4 acc[4] = {zero4, zero4, zero4, zero4};

        for (int ph = 0; ph < 4; ++ph) {
            int k0 = ph * 64;
            __syncthreads();
#pragma unroll
            for (int u = 0; u < 2; ++u) {
                int q = u * 256 + tid;
                int row = q >> 3, kc = q & 7;
                const float* xs = &xb[row * 256 + k0 + kc * 8];
                f32x4 a0 = *(const f32x4*)xs;
                f32x4 a1 = *(const f32x4*)(xs + 4);
                short8 sh, sl;
#pragma unroll
                for (int j = 0; j < 4; ++j) {
                    unsigned short h0 = f2bf(a0[j]);
                    sh[j] = (short)h0; sl[j] = (short)f2bf(a0[j] - bf2f(h0));
                    unsigned short h1 = f2bf(a1[j]);
                    sh[4 + j] = (short)h1; sl[4 + j] = (short)f2bf(a1[j] - bf2f(h1));
                }
                *(short8*)&sm[XH + row * 72 + kc * 8] = sh;
                *(short8*)&sm[XL + row * 72 + kc * 8] = sl;
                *(short8*)&sm[WH + row * 72 + kc * 8] =
                    *(const short8*)&wTh[row * 256 + k0 + kc * 8];
                *(short8*)&sm[WL + row * 72 + kc * 8] =
                    *(const short8*)&wTl[row * 256 + k0 + kc * 8];
            }
            __syncthreads();
#pragma unroll
            for (int ks = 0; ks < 2; ++ks) {
                short8 ah = *(const short8*)&sm[XH + (wave * 16 + lq) * 72 + ks * 32 + quad * 8];
                short8 al = *(const short8*)&sm[XL + (wave * 16 + lq) * 72 + ks * 32 + quad * 8];
#pragma unroll
                for (int ct = 0; ct < 4; ++ct) {
                    short8 bh = *(const short8*)&sm[WH + (lq + 16 * ct) * 72 + ks * 32 + quad * 8];
                    short8 bl = *(const short8*)&sm[WL + (lq + 16 * ct) * 72 + ks * 32 + quad * 8];
                    acc[ct] = __builtin_amdgcn_mfma_f32_16x16x32_bf16(ah, bh, acc[ct], 0, 0, 0);
                    acc[ct] = __builtin_amdgcn_mfma_f32_16x16x32_bf16(al, bh, acc[ct], 0, 0, 0);
                    acc[ct] = __builtin_amdgcn_mfma_f32_16x16x32_bf16(ah, bl, acc[ct], 0, 0, 0);
                }
            }
        }

        int rowl = wave * 16 + quad * 4;
#pragma unroll
        for (int ct = 0; ct < 4; ++ct) {
            int coll = lq + 16 * ct;
#pragma unroll
            for (int r = 0; r < 4; ++r) {
                int grow = rt * 64 + rowl + r;
                int bidx = grow >> 12, n = grow & 4095;
                float v = acc[ct][r];
                size_t o = (size_t)(bidx * 256 + (n >> 4)) * 512 +
                           (((coll & 31) >> 3) * 16 + (n & 15)) * 8 + (coll & 7);
                if (coll < 32) {
                    v += bfb[coll];
                    unsigned short h = f2bf(v);
                    fKh[o] = h;
                    fKl[o] = f2bf(v - bf2f(h));
                } else {
                    int cg = coll - 32;
                    size_t og = (size_t)(bidx * 256 + (n >> 4)) * 512 +
                                ((cg >> 3) * 16 + (n & 15)) * 8 + (cg & 7);
                    v += bgb[cg];
                    unsigned short h = f2bf(v);
                    gQh[og] = h;
                    gQl[og] = f2bf(v - bf2f(h));
                }
            }
        }
    }
}

// ---------------- kernel C: flash attention (R0 schedule, 128-reg class) ---
// Grid 512 x 512 thr -> (b = bid&3 [XCD affinity], qt [64-row q tile],
// ks = key half). 8 waves; wave w = (rs=w>>1 row-strip, kh=w&1 key-half):
// S = 2 16x16 tiles (6 hi/lo MFMA), PV = 64 rows x 32 channels (16 MFMA).
// acc = 8 f32x4 = 32 AGPR; target total regs <= 128 -> 4 waves/SIMD ->
// 16 waves/CU from 2 INDEPENDENT blocks (vs R0's 156 regs -> 256-class ->
// only 8 waves/CU). Same 64-key phases, one barrier/phase, 352 MFMA per
// CU-phase as R0 -- only the register class and wave count change.
#define PSTR 72
__global__ __launch_bounds__(512, 4) void k_attn(
    const unsigned short* __restrict__ fKh,
    const unsigned short* __restrict__ fKl,
    const unsigned short* __restrict__ gQh,
    const unsigned short* __restrict__ gQl,
    const unsigned short* __restrict__ hT,
    float* __restrict__ pacc0,
    float* __restrict__ pacc1,
    float* __restrict__ pl) {
    __shared__ short Ps[2][64 * PSTR];   // 18.4 KB dbuf P (64x64 pad 72)
    __shared__ short Fb[2][2][2048];     // 16 KB dbuf f hi/lo (64x32 frag-linear)
    __shared__ float Lred[4][16][2];     // 512 B l cross-wave (kh) reduce
    int tid = threadIdx.x;
    int wave = tid >> 6, lane = tid & 63, lq = lane & 15, quad = lane >> 4;
    int b = blockIdx.x & 3;
    int rest = blockIdx.x >> 2;
    int qt = rest & 63;
    int ks = rest >> 6;                  // 0 or 1 (key half)
    int rs = wave >> 1;                  // row strip 0..3 (16 rows)
    int kh = wave & 1;                   // key-half of phase (kt4 pair)
    int lchunk = quad * 16 + lq;         // fragment chunk index for this lane

    const unsigned short* fhB = fKh + (size_t)b * 131072;
    const unsigned short* flB = fKl + (size_t)b * 131072;
    const unsigned short* hB  = hT + (size_t)b * 1048576;
    float* pacc = ks ? pacc1 : pacc0;
    float* plb  = pl + ks * 16384;

    f32x4 zero4 = {0.f, 0.f, 0.f, 0.f};
    f32x4 acc[8];                        // [rb(4)][ct(2)] : 64 rows x 32 ch
#pragma unroll
    for (int i = 0; i < 8; ++i) acc[i] = zero4;
    float l_part[4] = {0.f, 0.f, 0.f, 0.f};

    // g A-frags: row-tile of this wave's strip
    int gtile = b * 256 + qt * 4 + rs;
    short8 ghfrag = *(const short8*)&gQh[(size_t)gtile * 512 + lchunk * 8];
    short8 glfrag = *(const short8*)&gQl[(size_t)gtile * 512 + lchunk * 8];

    // f staging: waves 0-3 stage hi, waves 4-7 stage lo (wave-uniform split)
    int sid = tid & 255;
    int hl = tid >> 8;
    const unsigned short* fB0 = hl ? flB : fhB;
    int ft0 = ks * 128;                  // first 16-key f tile of this half

    // prologue: stage f(kt=0): 4 tiles = 2048 shorts per hi/lo
    *(short8*)&Fb[0][hl][sid * 8] = *(const short8*)&fB0[(size_t)ft0 * 512 + sid * 8];
    __syncthreads();

    for (int kt = 0; kt < 32; ++kt) {
        int p = kt & 1;
        // ---- next-f prefetch (linear) ----
        int nft = ft0 + (kt < 31 ? kt + 1 : kt) * 4;
        short8 fn = *(const short8*)&fB0[(size_t)nft * 512 + sid * 8];

        // ---- hT B-frags: this wave's 2 channel-tiles x 2 key-groups ----
        int k0 = ks * 64 + kt * 2;       // key-group (32 keys) base
        int ct0 = wave * 2;
        short8 hb00 = *(const short8*)&hB[(((size_t)(ct0 + 0) * 128 + k0 + 0) * 64 + lchunk) * 8];
        short8 hb01 = *(const short8*)&hB[(((size_t)(ct0 + 0) * 128 + k0 + 1) * 64 + lchunk) * 8];
        short8 hb10 = *(const short8*)&hB[(((size_t)(ct0 + 1) * 128 + k0 + 0) * 64 + lchunk) * 8];
        short8 hb11 = *(const short8*)&hB[(((size_t)(ct0 + 1) * 128 + k0 + 1) * 64 + lchunk) * 8];

        // ---- S = g.f^T (3-term hi/lo), 2 tiles: kt4 = kh*2 + {0,1} ----
        short8 fh0 = *(const short8*)&Fb[p][0][(kh * 2 + 0) * 512 + lchunk * 8];
        short8 fl0 = *(const short8*)&Fb[p][1][(kh * 2 + 0) * 512 + lchunk * 8];
        short8 fh1 = *(const short8*)&Fb[p][0][(kh * 2 + 1) * 512 + lchunk * 8];
        short8 fl1 = *(const short8*)&Fb[p][1][(kh * 2 + 1) * 512 + lchunk * 8];
        f32x4 S0 = __builtin_amdgcn_mfma_f32_16x16x32_bf16(ghfrag, fh0, zero4, 0, 0, 0);
        f32x4 S1 = __builtin_amdgcn_mfma_f32_16x16x32_bf16(ghfrag, fh1, zero4, 0, 0, 0);
        S0 = __builtin_amdgcn_mfma_f32_16x16x32_bf16(glfrag, fh0, S0, 0, 0, 0);
        S1 = __builtin_amdgcn_mfma_f32_16x16x32_bf16(glfrag, fh1, S1, 0, 0, 0);
        S0 = __builtin_amdgcn_mfma_f32_16x16x32_bf16(ghfrag, fl0, S0, 0, 0, 0);
        S1 = __builtin_amdgcn_mfma_f32_16x16x32_bf16(ghfrag, fl1, S1, 0, 0, 0);

        // ---- P = exp(S), per-lane l, bf16 to LDS ----
#pragma unroll
        for (int r = 0; r < 4; ++r) {
            S0[r] = __expf(S0[r]);
            S1[r] = __expf(S1[r]);
            l_part[r] += S0[r] + S1[r];
        }
#pragma unroll
        for (int r = 0; r < 4; ++r) {
            int row = rs * 16 + quad * 4 + r;
            Ps[p][row * PSTR + (kh * 2 + 0) * 16 + lq] = (short)f2bf(S0[r]);
            Ps[p][row * PSTR + (kh * 2 + 1) * 16 + lq] = (short)f2bf(S1[r]);
        }

        // ---- stage next f ----
        *(short8*)&Fb[1 - p][hl][sid * 8] = fn;

        __syncthreads();   // P[p] + Fb[1-p] visible; single barrier per phase

        // ---- PV: all 64 rows x this wave's 32 channels ----
#pragma unroll
        for (int rb = 0; rb < 4; ++rb) {
            short8 pa0 = *(const short8*)&Ps[p][(rb * 16 + lq) * PSTR + quad * 8];
            short8 pa1 = *(const short8*)&Ps[p][(rb * 16 + lq) * PSTR + 32 + quad * 8];
            acc[rb * 2 + 0] = __builtin_amdgcn_mfma_f32_16x16x32_bf16(pa0, hb00, acc[rb * 2 + 0], 0, 0, 0);
            acc[rb * 2 + 0] = __builtin_amdgcn_mfma_f32_16x16x32_bf16(pa1, hb01, acc[rb * 2 + 0], 0, 0, 0);
            acc[rb * 2 + 1] = __builtin_amdgcn_mfma_f32_16x16x32_bf16(pa0, hb10, acc[rb * 2 + 1], 0, 0, 0);
            acc[rb * 2 + 1] = __builtin_amdgcn_mfma_f32_16x16x32_bf16(pa1, hb11, acc[rb * 2 + 1], 0, 0, 0);
        }
    }

    // ---- epilogue: reduce l over lq lanes, combine kh halves via LDS ----
#pragma unroll
    for (int r = 0; r < 4; ++r) {
        float s = l_part[r];
        s += __shfl_xor(s, 1);
        s += __shfl_xor(s, 2);
        s += __shfl_xor(s, 4);
        s += __shfl_xor(s, 8);
        if (lq == 0) Lred[rs][quad * 4 + r][kh] = s;
    }
    __syncthreads();
    if (kh == 0 && lq == 0) {
#pragma unroll
        for (int r = 0; r < 4; ++r) {
            int rl = quad * 4 + r;
            plb[b * 4096 + qt * 64 + rs * 16 + rl] = Lred[rs][rl][0] + Lred[rs][rl][1];
        }
    }

    // ---- write partials: this wave's 32 channels x 64 rows ----
#pragma unroll
    for (int rb = 0; rb < 4; ++rb)
#pragma unroll
        for (int ct = 0; ct < 2; ++ct) {
            int c = wave * 32 + ct * 16 + lq;
#pragma unroll
            for (int r = 0; r < 4; ++r) {
                int n = qt * 64 + rb * 16 + quad * 4 + r;
                pacc[((size_t)(b * 4096 + n)) * 256 + c] = acc[rb * 2 + ct][r];
            }
        }
}

// ---------------- kernel D: combine partials + residual --------------------
__global__ __launch_bounds__(256) void k_combine(
    const float* __restrict__ x,
    const float* __restrict__ gam_p,
    const float* __restrict__ pacc1,
    const float* __restrict__ pl,
    float* __restrict__ out) {
    int gid = blockIdx.x * 256 + threadIdx.x;
    int row = gid >> 6;
    f32x4 a0 = *(const f32x4*)&out[(size_t)gid * 4];
    f32x4 a1 = *(const f32x4*)&pacc1[(size_t)gid * 4];
    f32x4 xv = *(const f32x4*)&x[(size_t)gid * 4];
    float linv = 1.0f / (pl[row] + pl[16384 + row]);
    float gam = gam_p[0];
    f32x4 o;
#pragma unroll
    for (int j = 0; j < 4; ++j) o[j] = gam * ((a0[j] + a1[j]) * linv) + xv[j];
    *(f32x4*)&out[(size_t)gid * 4] = o;
}

extern "C" void kernel_launch(void* const* d_in, const int* in_sizes, int n_in,
                              void* d_out, int out_size, void* d_ws, size_t ws_size,
                              hipStream_t stream) {
    const float* x   = (const float*)d_in[0];
    const float* Wf  = (const float*)d_in[1];
    const float* bfb = (const float*)d_in[2];
    const float* Wg  = (const float*)d_in[3];
    const float* bgb = (const float*)d_in[4];
    const float* Wh  = (const float*)d_in[5];
    const float* bhb = (const float*)d_in[6];
    const float* gam = (const float*)d_in[7];
    float* out = (float*)d_out;

    char* ws = (char*)d_ws;
    const size_t MI = 1u << 20;
    unsigned short* fKh = (unsigned short*)(ws);                  // 1 MiB
    unsigned short* fKl = (unsigned short*)(ws + 1 * MI);         // 1 MiB
    unsigned short* gQh = (unsigned short*)(ws + 2 * MI);         // 1 MiB
    unsigned short* gQl = (unsigned short*)(ws + 3 * MI);         // 1 MiB
    unsigned short* hT  = (unsigned short*)(ws + 4 * MI);         // 8 MiB
    unsigned short* wTh = (unsigned short*)(ws + 12 * MI);        // 160 KiB
    unsigned short* wTl = (unsigned short*)(ws + 12 * MI + 160 * 1024); // 32 KiB
    float* pacc1 = (float*)(ws + 13 * MI);                        // 16 MiB
    float* pl    = (float*)(ws + 29 * MI);                        // 128 KiB

    k_prew<<<dim3(320), dim3(256), 0, stream>>>(Wf, Wg, Wh, wTh, wTl);
    k_proj<<<dim3(256, 5), dim3(256), 0, stream>>>(x, wTh, wTl, bfb, bgb, bhb,
                                                   fKh, fKl, gQh, gQl, hT);
    k_attn<<<dim3(512), dim3(512), 0, stream>>>(fKh, fKl, gQh, gQl, hT,
                                                out, pacc1, pl);
    k_combine<<<dim3(4096), dim3(256), 0, stream>>>(x, gam, pacc1, pl, out);
}